// Round 5
// baseline (3274.739 us; speedup 1.0000x reference)
//
#include <hip/hip_runtime.h>
#include <hip/hip_bf16.h>
#include <hip/hip_cooperative_groups.h>

namespace cg = cooperative_groups;

typedef __hip_bfloat16 bf16;
typedef __attribute__((ext_vector_type(4))) float f32x4;
typedef __attribute__((ext_vector_type(8))) short s16x8;

__device__ __forceinline__ float sigf(float x) {
    return 1.0f / (1.0f + __expf(-x));
}
__device__ __forceinline__ float tanh_f(float x) {
    float ax = fabsf(x);
    float e = __expf(-2.0f * ax);
    float r = (1.0f - e) / (1.0f + e);
    return x < 0.0f ? -r : r;
}

#define GLL16(src, ldst)                                                      \
    __builtin_amdgcn_global_load_lds(                                         \
        (const __attribute__((address_space(1))) void*)(src),                 \
        (__attribute__((address_space(3))) void*)(ldst), 16, 0, 0)

// ---------------------------------------------------------------------------
// embW[d][v][n] = sum_e emb[v][e]*W1[e][orig(n)] + b1[orig(n)], n = u*4+g
// ---------------------------------------------------------------------------
__global__ void k_embw(const float* __restrict__ emb,
                       const float* __restrict__ W1f, const float* __restrict__ b1f,
                       const float* __restrict__ W1b, const float* __restrict__ b1b,
                       float* __restrict__ embW) {
    int c = blockIdx.x * 256 + threadIdx.x;
    int v = blockIdx.y;
    int d = blockIdx.z;
    const float* W = d ? W1b : W1f;
    const float* b = d ? b1b : b1f;
    float acc = b[c];
    const float* er = emb + v * 128;
#pragma unroll 8
    for (int e = 0; e < 128; ++e) acc += er[e] * W[e * 2048 + c];
    int n = ((c & 511) << 2) | (c >> 9);
    embW[(d * 30 + v) * 2048 + n] = acc;
}

// b2r[d][n] = b2[d][orig(n)]
__global__ void k_b2r(const float* __restrict__ b2f, const float* __restrict__ b2b,
                      float* __restrict__ dst) {
    int i = blockIdx.x * 256 + threadIdx.x;
    int d = i >> 11, n = i & 2047;
    int c = ((n & 3) << 9) | (n >> 2);
    dst[i] = (d ? b2b : b2f)[c];
}

// ---------------------------------------------------------------------------
// Transpose(+gate reorder, +optional XOR swizzle) f32 [K][ncols] ->
// bf16 [ncols][kpitch] at koff.
// ---------------------------------------------------------------------------
template<int REORDER, int XOR>
__global__ void k_trans(const float* __restrict__ src, bf16* __restrict__ dst,
                        int ncols, int kpitch, int koff) {
    __shared__ float tile[64][65];
    int k0 = blockIdx.x * 64;
    int c0 = blockIdx.y * 64;
    int tid = threadIdx.x;
#pragma unroll
    for (int i = 0; i < 16; ++i) {
        int seg = tid + i * 256;
        int r = seg >> 6, cc = seg & 63;
        tile[r][cc] = src[(size_t)(k0 + r) * ncols + c0 + cc];
    }
    __syncthreads();
#pragma unroll
    for (int i = 0; i < 16; ++i) {
        int seg = tid + i * 256;
        int nl = seg >> 6, kl = seg & 63;
        int c = c0 + nl;
        int n = REORDER ? (((c & 511) << 2) | (c >> 9)) : c;
        int kabs = koff + k0 + kl;
        int ks = XOR ? (kabs ^ ((n & 7) << 3)) : kabs;
        dst[(size_t)n * kpitch + ks] = __float2bfloat16(tile[kl][nl]);
    }
}

// ---------------------------------------------------------------------------
// Persistent LSTM layer kernel over timesteps [t0, t1).
// Cooperative path: one launch with [0,64), grid.sync() between steps.
// Fallback path: 64 normal launches with [t,t+1) -> grid.sync never executed.
// Block owns (m0 128 rows, n0 128 gate-cols); wave wv owns 32 cols; recurrent
// B (K=512) is register-resident (bres). LAYER 2 adds W2 (K=1024) streamed
// through LDS from XOR-swizzled W2t.
// ---------------------------------------------------------------------------
template<int LAYER>
__global__ __launch_bounds__(256, 1)
void l_run(const bf16* __restrict__ Bres, const bf16* __restrict__ W2t,
           bf16* __restrict__ h1s, const float* __restrict__ table,
           const int* __restrict__ xin, float* __restrict__ c_st,
           bf16* __restrict__ h0, bf16* __restrict__ h1, int t0, int t1)
{
    cg::grid_group grid = cg::this_grid();
    constexpr int NCH = (LAYER == 1) ? 8 : 24;   // 64-K chunks

    __shared__ __align__(16) short ldss[32768];  // 64 KB

    const int tid  = threadIdx.x;
    const int lane = tid & 63;
    const int wv   = tid >> 6;
    const int xcd  = blockIdx.x & 7, yy = blockIdx.x >> 3;
    const int n0   = ((xcd << 1) | (yy >> 4)) << 7;
    const int m0   = (yy & 15) << 7;
    const int dir  = (m0 >= 1024);
    const int rl   = lane & 15;
    const int q8   = (lane >> 4) << 3;
    const int xk   = (rl & 7) << 3;
    const int u0   = n0 >> 2;

    // resident recurrent-B fragments: col n0+wv*32+fn*16+rl, k = ks*32+q8+j
    s16x8 bres[2][16];
    {
        const bf16* bp = Bres + ((size_t)dir * 2048 + n0 + (wv << 5) + rl) * 512 + q8;
#pragma unroll
        for (int fn = 0; fn < 2; ++fn)
#pragma unroll
            for (int ks = 0; ks < 16; ++ks)
                bres[fn][ks] = *(const s16x8*)(bp + fn * (16 * 512) + ks * 32);
    }

    const char* const btb = (LAYER == 2)
        ? (const char*)(W2t + ((size_t)dir * 2048 + n0) * 1024) : nullptr;

#pragma unroll 1
    for (int t = t0; t < t1; ++t) {
        const bf16* hin  = (t & 1) ? h1 : h0;
        bf16*       hout = (t & 1) ? h0 : h1;
        const int t_a = dir ? 63 - t : t;
        const char* a1b = nullptr;
        if (LAYER == 2)
            a1b = (const char*)(h1s + ((size_t)t_a << 20) + ((size_t)(m0 & 1023) << 10));
        const char* const arb = (const char*)(hin + (size_t)m0 * 512);

        auto stage = [&](int c, int buf) {
#pragma unroll
            for (int i = 0; i < 4; ++i) {
                const int u = i * 256 + tid;
                const int r = u >> 3, j = u & 7;
                const char* src;
                if (LAYER == 1)
                    src = arb + r * 1024 + c * 128 + j * 16;
                else
                    src = (c < 16) ? a1b + r * 2048 + c * 128 + j * 16
                                   : arb + r * 1024 + (c - 16) * 128 + j * 16;
                GLL16(src, (char*)ldss + buf * 16384 + (i * 256 + wv * 64) * 16);
            }
            if (LAYER == 2 && c < 16) {
#pragma unroll
                for (int i = 0; i < 4; ++i) {
                    const int u = i * 256 + tid;
                    const int r = u >> 3, j = u & 7;
                    GLL16(btb + (size_t)r * 2048 + c * 128 + j * 16,
                          (char*)ldss + 32768 + buf * 16384 + (i * 256 + wv * 64) * 16);
                }
            }
        };

        f32x4 acc[8][2];
#pragma unroll
        for (int i = 0; i < 8; ++i) {
            acc[i][0] = (f32x4){0.f, 0.f, 0.f, 0.f};
            acc[i][1] = (f32x4){0.f, 0.f, 0.f, 0.f};
        }

        stage(0, 0);

        if constexpr (LAYER == 2) {
            // phase A: W2 part (chunks 0..15), B via LDS
#pragma unroll 2
            for (int c = 0; c < 16; ++c) {
                __syncthreads();
                stage(c + 1, (c + 1) & 1);
                const short* as = ldss + (c & 1) * 8192;
                const short* bs = ldss + 16384 + (c & 1) * 8192;
#pragma unroll
                for (int ks = 0; ks < 2; ++ks) {
                    const int eo = ((ks << 5) + q8) ^ xk;
                    s16x8 af[8], bq[2];
#pragma unroll
                    for (int f = 0; f < 8; ++f)
                        af[f] = *(const s16x8*)&as[(f * 16 + rl) * 64 + eo];
#pragma unroll
                    for (int fn = 0; fn < 2; ++fn)
                        bq[fn] = *(const s16x8*)&bs[((wv << 5) + fn * 16 + rl) * 64 + eo];
#pragma unroll
                    for (int fm = 0; fm < 8; ++fm)
#pragma unroll
                        for (int fn = 0; fn < 2; ++fn)
                            acc[fm][fn] = __builtin_amdgcn_mfma_f32_16x16x32_bf16(
                                af[fm], bq[fn], acc[fm][fn], 0, 0, 0);
                }
            }
            // phase B: recurrent part (chunks 16..23), resident B
#pragma unroll
            for (int cc = 0; cc < 8; ++cc) {
                const int c = 16 + cc;
                __syncthreads();
                if (c + 1 < NCH) stage(c + 1, (c + 1) & 1);
                const short* as = ldss + (c & 1) * 8192;
#pragma unroll
                for (int ks = 0; ks < 2; ++ks) {
                    const int eo = ((ks << 5) + q8) ^ xk;
                    s16x8 af[8];
#pragma unroll
                    for (int f = 0; f < 8; ++f)
                        af[f] = *(const s16x8*)&as[(f * 16 + rl) * 64 + eo];
#pragma unroll
                    for (int fm = 0; fm < 8; ++fm)
#pragma unroll
                        for (int fn = 0; fn < 2; ++fn)
                            acc[fm][fn] = __builtin_amdgcn_mfma_f32_16x16x32_bf16(
                                af[fm], bres[fn][cc * 2 + ks], acc[fm][fn], 0, 0, 0);
                }
            }
        } else {
            // layer 1: recurrent only, resident B
#pragma unroll
            for (int c = 0; c < 8; ++c) {
                __syncthreads();
                if (c + 1 < NCH) stage(c + 1, (c + 1) & 1);
                const short* as = ldss + (c & 1) * 8192;
#pragma unroll
                for (int ks = 0; ks < 2; ++ks) {
                    const int eo = ((ks << 5) + q8) ^ xk;
                    s16x8 af[8];
#pragma unroll
                    for (int f = 0; f < 8; ++f)
                        af[f] = *(const s16x8*)&as[(f * 16 + rl) * 64 + eo];
#pragma unroll
                    for (int fm = 0; fm < 8; ++fm)
#pragma unroll
                        for (int fn = 0; fn < 2; ++fn)
                            acc[fm][fn] = __builtin_amdgcn_mfma_f32_16x16x32_bf16(
                                af[fm], bres[fn][c * 2 + ks], acc[fm][fn], 0, 0, 0);
                }
            }
        }

        // ---- gates epilogue (fully unrolled: static acc indexing) ----
        float* z = (float*)ldss;   // [64][132] f32 = 33792 B
#pragma unroll
        for (int half = 0; half < 2; ++half) {
            __syncthreads();
#pragma unroll
            for (int fm = 0; fm < 4; ++fm) {
                const int zr = fm * 16 + ((lane >> 4) << 2);
#pragma unroll
                for (int fn = 0; fn < 2; ++fn) {
                    const int zc = (wv << 5) + fn * 16 + rl;
#pragma unroll
                    for (int r = 0; r < 4; ++r)
                        z[(zr + r) * 132 + zc] = acc[half * 4 + fm][fn][r];
                }
            }
            __syncthreads();
#pragma unroll 2
            for (int j = 0; j < 8; ++j) {
                const int cid = j * 256 + tid;
                const int ml = cid >> 5;
                const int ul = cid & 31;
                const int mg = m0 + half * 64 + ml;
                const int b  = mg & 1023;
                float4 z4 = *(float4*)&z[ml * 132 + (ul << 2)];
                const float* tab;
                if constexpr (LAYER == 1) {
                    const int v = xin[(b << 6) + t_a];
                    tab = table + (size_t)(dir * 30 + v) * 2048;
                } else {
                    tab = table + dir * 2048;
                }
                const float4 tv = *(const float4*)&tab[n0 + (ul << 2)];
                const float zi = z4.x + tv.x, zf = z4.y + tv.y;
                const float zg = z4.z + tv.z, zo = z4.w + tv.w;
                const float ig = sigf(zi), fg = sigf(zf);
                const float gg = tanh_f(zg), og = sigf(zo);
                const size_t cu = (size_t)mg * 512 + u0 + ul;
                const float cn = fg * c_st[cu] + ig * gg;
                c_st[cu] = cn;
                const float h = og * tanh_f(cn);
                const int us = (u0 + ul) ^ ((mg & 7) << 3);
                hout[(size_t)mg * 512 + us] = __float2bfloat16(h);
                if constexpr (LAYER == 1) {
                    const int col = (((dir << 9) | (u0 + ul)) ^ ((b & 7) << 3));
                    h1s[(((size_t)t_a << 10) + b) * 1024 + col] =
                        __float2bfloat16(h);
                }
            }
        }

        if (t + 1 < t1) {          // only on the cooperative multi-step path
            __threadfence();
            grid.sync();
        }
    }
}

// ---------------------------------------------------------------------------
// dense: dbuf[b][n] = relu([hf|hb][b] . Wd[:,n] + bd[n])  (K=1024, XOR inputs)
// ---------------------------------------------------------------------------
__global__ __launch_bounds__(256, 2)
void k_dense(const bf16* __restrict__ hin, const bf16* __restrict__ Bt,
             const float* __restrict__ bd, bf16* __restrict__ dbuf)
{
    __shared__ __align__(16) short ldss[32768];
    const int tid  = threadIdx.x;
    const int lane = tid & 63;
    const int wv   = tid >> 6;
    const int wm   = (wv >> 1) << 6;
    const int wn   = (wv & 1) << 6;
    const int n0   = (blockIdx.x & 7) << 7;
    const int m0   = (blockIdx.x >> 3) << 7;

    const char* const a1b = (const char*)(hin + (size_t)m0 * 512);
    const char* const a2b = (const char*)(hin + (size_t)1024 * 512);
    const char* const btb = (const char*)(Bt + (size_t)n0 * 1024);

    auto stage = [&](int c, int buf) {
#pragma unroll
        for (int i = 0; i < 4; ++i) {
            const int u = i * 256 + tid;
            const int r = u >> 3, j = u & 7;
            const char* src = (c < 8)
                ? a1b + r * 1024 + c * 128 + j * 16
                : a2b + (size_t)(m0 + r) * 1024 + (c - 8) * 128 + j * 16;
            GLL16(src, (char*)ldss + buf * 16384 + (i * 256 + wv * 64) * 16);
        }
#pragma unroll
        for (int i = 0; i < 4; ++i) {
            const int u = i * 256 + tid;
            const int r = u >> 3, j = u & 7;
            GLL16(btb + (size_t)r * 2048 + c * 128 + j * 16,
                  (char*)ldss + 32768 + buf * 16384 + (i * 256 + wv * 64) * 16);
        }
    };

    f32x4 acc[4][4];
#pragma unroll
    for (int i = 0; i < 4; ++i)
#pragma unroll
        for (int j = 0; j < 4; ++j) acc[i][j] = (f32x4){0.f, 0.f, 0.f, 0.f};

    stage(0, 0);
    const int rl = lane & 15;
    const int q8 = (lane >> 4) << 3;
    const int xk = (rl & 7) << 3;

#pragma unroll 2
    for (int c = 0; c < 16; ++c) {
        __syncthreads();
        if (c + 1 < 16) stage(c + 1, (c + 1) & 1);
        const short* as = ldss + (c & 1) * 8192;
        const short* bs = ldss + 16384 + (c & 1) * 8192;
#pragma unroll
        for (int ks = 0; ks < 2; ++ks) {
            const int eo = ((ks << 5) + q8) ^ xk;
            s16x8 af[4], bq[4];
#pragma unroll
            for (int f = 0; f < 4; ++f)
                af[f] = *(const s16x8*)&as[(wm + f * 16 + rl) * 64 + eo];
#pragma unroll
            for (int f = 0; f < 4; ++f)
                bq[f] = *(const s16x8*)&bs[(wn + f * 16 + rl) * 64 + eo];
#pragma unroll
            for (int fm = 0; fm < 4; ++fm)
#pragma unroll
                for (int fn = 0; fn < 4; ++fn)
                    acc[fm][fn] = __builtin_amdgcn_mfma_f32_16x16x32_bf16(
                        af[fm], bq[fn], acc[fm][fn], 0, 0, 0);
        }
    }

#pragma unroll
    for (int fn = 0; fn < 4; ++fn) {
        const int col = n0 + wn + fn * 16 + rl;
        const float bdv = bd[col];
#pragma unroll
        for (int fm = 0; fm < 4; ++fm) {
            const int rb = m0 + wm + fm * 16 + ((lane >> 4) << 2);
#pragma unroll
            for (int r = 0; r < 4; ++r) {
                float v = acc[fm][fn][r] + bdv;
                dbuf[(size_t)(rb + r) * 1024 + col] =
                    __float2bfloat16(v > 0.f ? v : 0.f);
            }
        }
    }
}

// ---------------------------------------------------------------------------
// out[b][o] = dbuf[b] . Wo[:,o] + bo[o]
// ---------------------------------------------------------------------------
__global__ __launch_bounds__(256)
void k_out(const bf16* __restrict__ dbuf, const float* __restrict__ Wo,
           const float* __restrict__ bo, float* __restrict__ out) {
    int b = blockIdx.x, tid = threadIdx.x;
    int wv = tid >> 6, lane = tid & 63;
    float acc[5] = {0.f, 0.f, 0.f, 0.f, 0.f};
    for (int kk = 0; kk < 1024; kk += 64) {
        float a = __bfloat162float(dbuf[b * 1024 + kk + lane]);
#pragma unroll
        for (int j = 0; j < 5; ++j)
            acc[j] += a * Wo[(kk + lane) * 20 + wv + j * 4];
    }
#pragma unroll
    for (int j = 0; j < 5; ++j) {
        float s = acc[j];
        for (int off = 32; off; off >>= 1) s += __shfl_down(s, off, 64);
        if (lane == 0) out[b * 20 + wv + j * 4] = s + bo[wv + j * 4];
    }
}

// ---------------------------------------------------------------------------
extern "C" void kernel_launch(void* const* d_in, const int* in_sizes, int n_in,
                              void* d_out, int out_size, void* d_ws, size_t ws_size,
                              hipStream_t stream) {
    const int*   x   = (const int*)  d_in[0];
    const float* emb = (const float*)d_in[1];
    const float* W1f = (const float*)d_in[2];
    const float* U1f = (const float*)d_in[3];
    const float* b1f = (const float*)d_in[4];
    const float* W1b = (const float*)d_in[5];
    const float* U1b = (const float*)d_in[6];
    const float* b1b = (const float*)d_in[7];
    const float* W2f = (const float*)d_in[8];
    const float* U2f = (const float*)d_in[9];
    const float* b2f = (const float*)d_in[10];
    const float* W2b = (const float*)d_in[11];
    const float* U2b = (const float*)d_in[12];
    const float* b2b = (const float*)d_in[13];
    const float* Wd  = (const float*)d_in[14];
    const float* bd  = (const float*)d_in[15];
    const float* Wo  = (const float*)d_in[16];
    const float* bo  = (const float*)d_in[17];

    char* ws = (char*)d_ws;
    float* embW = (float*)(ws + 0);               // [2][30][2048] f32
    float* b2r  = (float*)(ws + 491520);          // [2][2048] f32
    bf16* Ut1   = (bf16*)(ws + 507904);           // [2][2048][512]  plain
    bf16* Ut2   = (bf16*)(ws + 4702208);          // [2][2048][512]  plain
    bf16* W2t   = (bf16*)(ws + 8896512);          // [2][2048][1024] XOR
    bf16* Wdt   = (bf16*)(ws + 17285120);         // [1024][1024]    XOR
    bf16* hA    = (bf16*)(ws + 19382272);         // [2048][512]     XOR
    bf16* hB    = (bf16*)(ws + 21479424);         // [2048][512]     XOR
    float* cst  = (float*)(ws + 23576576);        // [2048][512] f32
    bf16* dbuf  = (bf16*)(ws + 27770880);         // [1024][1024]
    bf16* h1seq = (bf16*)(ws + 29868032);         // [64][1024][1024] XOR
    // end: 164,085,760 bytes

    // ---- prep ----
    k_embw<<<dim3(8, 30, 2), 256, 0, stream>>>(emb, W1f, b1f, W1b, b1b, embW);
    k_b2r<<<16, 256, 0, stream>>>(b2f, b2b, b2r);
    k_trans<1, 0><<<dim3(8, 32), 256, 0, stream>>>(U1f, Ut1,              2048, 512, 0);
    k_trans<1, 0><<<dim3(8, 32), 256, 0, stream>>>(U1b, Ut1 + 2048 * 512, 2048, 512, 0);
    k_trans<1, 0><<<dim3(8, 32), 256, 0, stream>>>(U2f, Ut2,              2048, 512, 0);
    k_trans<1, 0><<<dim3(8, 32), 256, 0, stream>>>(U2b, Ut2 + 2048 * 512, 2048, 512, 0);
    k_trans<1, 1><<<dim3(16, 32), 256, 0, stream>>>(W2f, W2t,               2048, 1024, 0);
    k_trans<1, 1><<<dim3(16, 32), 256, 0, stream>>>(W2b, W2t + 2048 * 1024, 2048, 1024, 0);
    k_trans<0, 1><<<dim3(16, 16), 256, 0, stream>>>(Wd, Wdt, 1024, 1024, 0);

    // ---- cooperative-launch feasibility (deterministic per environment) ----
    int dev = 0;
    hipGetDevice(&dev);
    int coopAttr = 0, cus = 0;
    hipDeviceGetAttribute(&coopAttr, hipDeviceAttributeCooperativeLaunch, dev);
    hipDeviceGetAttribute(&cus, hipDeviceAttributeMultiprocessorCount, dev);
    int nb1 = 0, nb2 = 0;
    hipOccupancyMaxActiveBlocksPerMultiprocessor(&nb1, l_run<1>, 256, 0);
    hipOccupancyMaxActiveBlocksPerMultiprocessor(&nb2, l_run<2>, 256, 0);
    const bool coop1 = coopAttr && nb1 > 0 && (long)nb1 * cus >= 256;
    const bool coop2 = coopAttr && nb2 > 0 && (long)nb2 * cus >= 256;

    // ---- layer 1 ----
    hipMemsetAsync(hA, 0, (size_t)2048 * 512 * sizeof(bf16), stream);
    hipMemsetAsync(cst, 0, (size_t)2048 * 512 * sizeof(float), stream);
    {
        const bf16* Bres = Ut1;  const bf16* w2 = nullptr;  bf16* h1sp = h1seq;
        const float* tab = embW; const int* xi = x;         float* cs = cst;
        bf16* h0p = hA;          bf16* h1p = hB;
        int t0 = 0, t1 = 64;
        bool done = false;
        if (coop1) {
            void* args[] = {&Bres, &w2, &h1sp, &tab, &xi, &cs, &h0p, &h1p, &t0, &t1};
            void (*f1)(const bf16*, const bf16*, bf16*, const float*, const int*,
                       float*, bf16*, bf16*, int, int) = l_run<1>;
            done = hipLaunchCooperativeKernel(reinterpret_cast<void*>(f1),
                                              dim3(256), dim3(256), args, 0,
                                              stream) == hipSuccess;
        }
        if (!done)
            for (int t = 0; t < 64; ++t)
                l_run<1><<<256, 256, 0, stream>>>(Ut1, (const bf16*)nullptr,
                                                  h1seq, embW, x, cst, hA, hB,
                                                  t, t + 1);
    }

    // ---- layer 2 ----
    hipMemsetAsync(hA, 0, (size_t)2048 * 512 * sizeof(bf16), stream);
    hipMemsetAsync(cst, 0, (size_t)2048 * 512 * sizeof(float), stream);
    {
        const bf16* Bres = Ut2;  const bf16* w2 = W2t;  bf16* h1sp = h1seq;
        const float* tab = b2r;  const int* xi = nullptr;  float* cs = cst;
        bf16* h0p = hA;          bf16* h1p = hB;
        int t0 = 0, t1 = 64;
        bool done = false;
        if (coop2) {
            void* args[] = {&Bres, &w2, &h1sp, &tab, &xi, &cs, &h0p, &h1p, &t0, &t1};
            void (*f2)(const bf16*, const bf16*, bf16*, const float*, const int*,
                       float*, bf16*, bf16*, int, int) = l_run<2>;
            done = hipLaunchCooperativeKernel(reinterpret_cast<void*>(f2),
                                              dim3(256), dim3(256), args, 0,
                                              stream) == hipSuccess;
        }
        if (!done)
            for (int t = 0; t < 64; ++t)
                l_run<2><<<256, 256, 0, stream>>>(Ut2, W2t, h1seq, b2r,
                                                  (const int*)nullptr, cst,
                                                  hA, hB, t, t + 1);
    }
    // final layer-2 h is in hA (t=63 writes buffer 0)

    // ---- dense + relu, then output projection ----
    k_dense<<<64, 256, 0, stream>>>(hA, Wdt, bd, dbuf);
    k_out<<<1024, 256, 0, stream>>>(dbuf, Wo, bo, (float*)d_out);
}

// Round 6
// 2169.522 us; speedup vs baseline: 1.5094x; 1.5094x over previous
//
#include <hip/hip_runtime.h>
#include <hip/hip_bf16.h>

typedef __hip_bfloat16 bf16;
typedef __attribute__((ext_vector_type(4))) float f32x4;
typedef __attribute__((ext_vector_type(8))) short s16x8;

__device__ __forceinline__ float sigf(float x) {
    return 1.0f / (1.0f + __expf(-x));
}
__device__ __forceinline__ float tanh_f(float x) {
    float ax = fabsf(x);
    float e = __expf(-2.0f * ax);
    float r = (1.0f - e) / (1.0f + e);
    return x < 0.0f ? -r : r;
}

#define GLL16(src, ldst)                                                      \
    __builtin_amdgcn_global_load_lds(                                         \
        (const __attribute__((address_space(1))) void*)(src),                 \
        (__attribute__((address_space(3))) void*)(ldst), 16, 0, 0)

// ---------------------------------------------------------------------------
// embW[d][v][n] = sum_e emb[v][e]*W1[e][orig(n)] + b1[orig(n)], n = u*4+g
// ---------------------------------------------------------------------------
__global__ void k_embw(const float* __restrict__ emb,
                       const float* __restrict__ W1f, const float* __restrict__ b1f,
                       const float* __restrict__ W1b, const float* __restrict__ b1b,
                       float* __restrict__ embW) {
    int c = blockIdx.x * 256 + threadIdx.x;
    int v = blockIdx.y;
    int d = blockIdx.z;
    const float* W = d ? W1b : W1f;
    const float* b = d ? b1b : b1f;
    float acc = b[c];
    const float* er = emb + v * 128;
#pragma unroll 8
    for (int e = 0; e < 128; ++e) acc += er[e] * W[e * 2048 + c];
    int n = ((c & 511) << 2) | (c >> 9);
    embW[(d * 30 + v) * 2048 + n] = acc;
}

// b2r[d][n] = b2[d][orig(n)]
__global__ void k_b2r(const float* __restrict__ b2f, const float* __restrict__ b2b,
                      float* __restrict__ dst) {
    int i = blockIdx.x * 256 + threadIdx.x;
    int d = i >> 11, n = i & 2047;
    int c = ((n & 3) << 9) | (n >> 2);
    dst[i] = (d ? b2b : b2f)[c];
}

// ---------------------------------------------------------------------------
// Transpose(+gate reorder, +XOR swizzle) f32 [K][ncols] -> bf16 [ncols][kpitch]
// ---------------------------------------------------------------------------
template<int REORDER, int XOR>
__global__ void k_trans(const float* __restrict__ src, bf16* __restrict__ dst,
                        int ncols, int kpitch, int koff) {
    __shared__ float tile[64][65];
    int k0 = blockIdx.x * 64;
    int c0 = blockIdx.y * 64;
    int tid = threadIdx.x;
#pragma unroll
    for (int i = 0; i < 16; ++i) {
        int seg = tid + i * 256;
        int r = seg >> 6, cc = seg & 63;
        tile[r][cc] = src[(size_t)(k0 + r) * ncols + c0 + cc];
    }
    __syncthreads();
#pragma unroll
    for (int i = 0; i < 16; ++i) {
        int seg = tid + i * 256;
        int nl = seg >> 6, kl = seg & 63;
        int c = c0 + nl;
        int n = REORDER ? (((c & 511) << 2) | (c >> 9)) : c;
        int kabs = koff + k0 + kl;
        int ks = XOR ? (kabs ^ ((n & 7) << 3)) : kabs;
        dst[(size_t)n * kpitch + ks] = __float2bfloat16(tile[kl][nl]);
    }
}

// ---------------------------------------------------------------------------
// LSTM step: 128(M) x 64(N-gate) tiles, grid 512 (2 blocks/CU), 64-K chunks,
// double-buffered global_load_lds staging from pre-XOR-swizzled operands.
// MODE 0: layer-1 (K=512,  A=h_in,            add=embW gather)
// MODE 1: layer-2 (K=1536, A=[h1seq[t]|h_in], add=bias)
// ---------------------------------------------------------------------------
template<int MODE>
__global__ __launch_bounds__(256, 2)
void k_step(const bf16* __restrict__ A1, const bf16* __restrict__ A2,
            const bf16* __restrict__ Bt, const float* __restrict__ table,
            const int* __restrict__ xin, float* __restrict__ c_st,
            bf16* __restrict__ h_out, bf16* __restrict__ h1s, int t)
{
    constexpr int NCH = (MODE == 0) ? 8 : 24;     // 64-K chunks
    constexpr int BP  = (MODE == 0) ? 512 : 1536; // B row pitch (elements)

    // 48 KB: 2 x (A[128][64] 16KB + B[64][64] 8KB); epilogue z overlays
    __shared__ __align__(16) short ldss[24576];

    const int tid  = threadIdx.x;
    const int lane = tid & 63;
    const int wv   = tid >> 6;
    const int wm   = wv << 5;                     // wave's 32-row window

    // XCD map: xcd owns 4 consecutive n-tiles (x16 m-tiles) -> B L2-resident
    const int xcd = blockIdx.x & 7, idx = blockIdx.x >> 3;
    const int n0  = ((xcd << 2) | (idx >> 4)) << 6;   // 64-wide gate window
    const int m0  = (idx & 15) << 7;                  // 128-row window

    const int dir = (m0 >= 1024);
    const int t_a = dir ? 63 - t : t;
    const int rl  = lane & 15;
    const int q8  = (lane >> 4) << 3;
    const int q4  = (lane >> 4) << 2;
    const int xk  = (rl & 7) << 3;
    const int u0  = n0 >> 2;                          // 16-u window start

    const char* a1b;
    if constexpr (MODE == 1)
        a1b = (const char*)(A1 + ((size_t)t_a << 20) + ((size_t)(m0 & 1023) << 10));
    else
        a1b = (const char*)(A1 + (size_t)m0 * 512);
    const char* const btb = (const char*)(Bt + ((size_t)dir * 2048 + n0) * BP);
    const char* const a2b = (const char*)A2;

    // stage chunk c: A 128x64 (4 iters) + B 64x64 (2 iters), 16 B per thread
    auto stage = [&](int c, int buf) {
        char* base = (char*)ldss + buf * 24576;
#pragma unroll
        for (int i = 0; i < 4; ++i) {
            const int u = i * 256 + tid;
            const int r = u >> 3, j = u & 7;
            const char* src;
            if constexpr (MODE == 0)
                src = a1b + r * 1024 + c * 128 + j * 16;
            else
                src = (c < 16) ? a1b + r * 2048 + c * 128 + j * 16
                               : a2b + (size_t)(m0 + r) * 1024 + (c - 16) * 128 + j * 16;
            GLL16(src, base + (i * 256 + wv * 64) * 16);
        }
#pragma unroll
        for (int i = 0; i < 2; ++i) {
            const int u = i * 256 + tid;
            const int r = u >> 3, j = u & 7;
            GLL16(btb + (size_t)r * (BP * 2) + c * 128 + j * 16,
                  base + 16384 + (i * 256 + wv * 64) * 16);
        }
    };

    f32x4 acc[2][4];
#pragma unroll
    for (int i = 0; i < 2; ++i)
#pragma unroll
        for (int j = 0; j < 4; ++j) acc[i][j] = (f32x4){0.f, 0.f, 0.f, 0.f};

    stage(0, 0);

    for (int c = 0; c < NCH; ++c) {
        __syncthreads();                 // buf[c&1] staged and visible
        if (c + 1 < NCH) stage(c + 1, (c + 1) & 1);
        const short* as = ldss + (c & 1) * 12288;
        const short* bs = as + 8192;
#pragma unroll
        for (int ks = 0; ks < 2; ++ks) {
            const int eo = ((ks << 5) + q8) ^ xk;
            s16x8 af[2], bq[4];
#pragma unroll
            for (int f = 0; f < 2; ++f)
                af[f] = *(const s16x8*)&as[(wm + f * 16 + rl) * 64 + eo];
#pragma unroll
            for (int f = 0; f < 4; ++f)
                bq[f] = *(const s16x8*)&bs[(f * 16 + rl) * 64 + eo];
#pragma unroll
            for (int fm = 0; fm < 2; ++fm)
#pragma unroll
                for (int fn = 0; fn < 4; ++fn)
                    acc[fm][fn] = __builtin_amdgcn_mfma_f32_16x16x32_bf16(
                        af[fm], bq[fn], acc[fm][fn], 0, 0, 0);
        }
    }

    // ---- gates epilogue: single z pass (waves own disjoint 32-row bands) ----
    float* z = (float*)ldss;   // [128][68] f32 = 34816 B < 49152 B
    __syncthreads();           // staging reads done -> safe to overlay
#pragma unroll
    for (int fm = 0; fm < 2; ++fm)
#pragma unroll
        for (int fn = 0; fn < 4; ++fn) {
            const int zr = wm + fm * 16 + q4;
            const int zc = fn * 16 + rl;
#pragma unroll
            for (int r = 0; r < 4; ++r)
                z[(zr + r) * 68 + zc] = acc[fm][fn][r];
        }
    __syncthreads();
#pragma unroll 2
    for (int j = 0; j < 8; ++j) {
        const int cid = j * 256 + tid;
        const int ml = cid >> 4;          // 0..127
        const int ul = cid & 15;          // 0..15
        const int mg = m0 + ml;
        const int b  = mg & 1023;
        float4 z4 = *(float4*)&z[ml * 68 + (ul << 2)];
        const float* tab;
        if constexpr (MODE == 0) {
            const int v = xin[(b << 6) + t_a];
            tab = table + (size_t)(dir * 30 + v) * 2048;
        } else {
            tab = table + dir * 2048;
        }
        const float4 tv = *(const float4*)&tab[n0 + (ul << 2)];
        const float zi = z4.x + tv.x, zf = z4.y + tv.y;
        const float zg = z4.z + tv.z, zo = z4.w + tv.w;
        const float ig = sigf(zi), fg = sigf(zf);
        const float gg = tanh_f(zg), og = sigf(zo);
        const int u = u0 + ul;
        const size_t cu = (size_t)mg * 512 + u;        // c_st unswizzled
        const float cn = fg * c_st[cu] + ig * gg;
        c_st[cu] = cn;
        const float h = og * tanh_f(cn);
        const int us = u ^ ((mg & 7) << 3);            // pre-swizzled h store
        h_out[(size_t)mg * 512 + us] = __float2bfloat16(h);
        if constexpr (MODE == 0) {
            const int col = (((dir << 9) | u) ^ ((b & 7) << 3));
            h1s[(((size_t)t_a << 10) + b) * 1024 + col] = __float2bfloat16(h);
        }
    }
}

// ---------------------------------------------------------------------------
// dense: dbuf[b][n] = relu([hf|hb][b] . Wd[:,n] + bd[n])  (K=1024, XOR inputs)
// ---------------------------------------------------------------------------
__global__ __launch_bounds__(256, 2)
void k_dense(const bf16* __restrict__ hin, const bf16* __restrict__ Bt,
             const float* __restrict__ bd, bf16* __restrict__ dbuf)
{
    __shared__ __align__(16) short ldss[32768];
    const int tid  = threadIdx.x;
    const int lane = tid & 63;
    const int wv   = tid >> 6;
    const int wm   = (wv >> 1) << 6;
    const int wn   = (wv & 1) << 6;
    const int n0   = (blockIdx.x & 7) << 7;
    const int m0   = (blockIdx.x >> 3) << 7;

    const char* const a1b = (const char*)(hin + (size_t)m0 * 512);
    const char* const a2b = (const char*)(hin + (size_t)1024 * 512);
    const char* const btb = (const char*)(Bt + (size_t)n0 * 1024);

    auto stage = [&](int c, int buf) {
#pragma unroll
        for (int i = 0; i < 4; ++i) {
            const int u = i * 256 + tid;
            const int r = u >> 3, j = u & 7;
            const char* src = (c < 8)
                ? a1b + r * 1024 + c * 128 + j * 16
                : a2b + (size_t)(m0 + r) * 1024 + (c - 8) * 128 + j * 16;
            GLL16(src, (char*)ldss + buf * 16384 + (i * 256 + wv * 64) * 16);
        }
#pragma unroll
        for (int i = 0; i < 4; ++i) {
            const int u = i * 256 + tid;
            const int r = u >> 3, j = u & 7;
            GLL16(btb + (size_t)r * 2048 + c * 128 + j * 16,
                  (char*)ldss + 32768 + buf * 16384 + (i * 256 + wv * 64) * 16);
        }
    };

    f32x4 acc[4][4];
#pragma unroll
    for (int i = 0; i < 4; ++i)
#pragma unroll
        for (int j = 0; j < 4; ++j) acc[i][j] = (f32x4){0.f, 0.f, 0.f, 0.f};

    stage(0, 0);
    const int rl = lane & 15;
    const int q8 = (lane >> 4) << 3;
    const int xk = (rl & 7) << 3;

#pragma unroll 2
    for (int c = 0; c < 16; ++c) {
        __syncthreads();
        if (c + 1 < 16) stage(c + 1, (c + 1) & 1);
        const short* as = ldss + (c & 1) * 8192;
        const short* bs = ldss + 16384 + (c & 1) * 8192;
#pragma unroll
        for (int ks = 0; ks < 2; ++ks) {
            const int eo = ((ks << 5) + q8) ^ xk;
            s16x8 af[4], bq[4];
#pragma unroll
            for (int f = 0; f < 4; ++f)
                af[f] = *(const s16x8*)&as[(wm + f * 16 + rl) * 64 + eo];
#pragma unroll
            for (int f = 0; f < 4; ++f)
                bq[f] = *(const s16x8*)&bs[(wn + f * 16 + rl) * 64 + eo];
#pragma unroll
            for (int fm = 0; fm < 4; ++fm)
#pragma unroll
                for (int fn = 0; fn < 4; ++fn)
                    acc[fm][fn] = __builtin_amdgcn_mfma_f32_16x16x32_bf16(
                        af[fm], bq[fn], acc[fm][fn], 0, 0, 0);
        }
    }

#pragma unroll
    for (int fn = 0; fn < 4; ++fn) {
        const int col = n0 + wn + fn * 16 + rl;
        const float bdv = bd[col];
#pragma unroll
        for (int fm = 0; fm < 4; ++fm) {
            const int rb = m0 + wm + fm * 16 + ((lane >> 4) << 2);
#pragma unroll
            for (int r = 0; r < 4; ++r) {
                float v = acc[fm][fn][r] + bdv;
                dbuf[(size_t)(rb + r) * 1024 + col] =
                    __float2bfloat16(v > 0.f ? v : 0.f);
            }
        }
    }
}

// ---------------------------------------------------------------------------
// out[b][o] = dbuf[b] . Wo[:,o] + bo[o]
// ---------------------------------------------------------------------------
__global__ __launch_bounds__(256)
void k_out(const bf16* __restrict__ dbuf, const float* __restrict__ Wo,
           const float* __restrict__ bo, float* __restrict__ out) {
    int b = blockIdx.x, tid = threadIdx.x;
    int wv = tid >> 6, lane = tid & 63;
    float acc[5] = {0.f, 0.f, 0.f, 0.f, 0.f};
    for (int kk = 0; kk < 1024; kk += 64) {
        float a = __bfloat162float(dbuf[b * 1024 + kk + lane]);
#pragma unroll
        for (int j = 0; j < 5; ++j)
            acc[j] += a * Wo[(kk + lane) * 20 + wv + j * 4];
    }
#pragma unroll
    for (int j = 0; j < 5; ++j) {
        float s = acc[j];
        for (int off = 32; off; off >>= 1) s += __shfl_down(s, off, 64);
        if (lane == 0) out[b * 20 + wv + j * 4] = s + bo[wv + j * 4];
    }
}

// ---------------------------------------------------------------------------
extern "C" void kernel_launch(void* const* d_in, const int* in_sizes, int n_in,
                              void* d_out, int out_size, void* d_ws, size_t ws_size,
                              hipStream_t stream) {
    const int*   x   = (const int*)  d_in[0];
    const float* emb = (const float*)d_in[1];
    const float* W1f = (const float*)d_in[2];
    const float* U1f = (const float*)d_in[3];
    const float* b1f = (const float*)d_in[4];
    const float* W1b = (const float*)d_in[5];
    const float* U1b = (const float*)d_in[6];
    const float* b1b = (const float*)d_in[7];
    const float* W2f = (const float*)d_in[8];
    const float* U2f = (const float*)d_in[9];
    const float* b2f = (const float*)d_in[10];
    const float* W2b = (const float*)d_in[11];
    const float* U2b = (const float*)d_in[12];
    const float* b2b = (const float*)d_in[13];
    const float* Wd  = (const float*)d_in[14];
    const float* bd  = (const float*)d_in[15];
    const float* Wo  = (const float*)d_in[16];
    const float* bo  = (const float*)d_in[17];

    char* ws = (char*)d_ws;
    float* embW = (float*)(ws + 0);               // [2][30][2048] f32
    float* b2r  = (float*)(ws + 491520);          // [2][2048] f32
    bf16* Ut1   = (bf16*)(ws + 507904);           // [2][2048][512]  XOR
    bf16* BigBt = (bf16*)(ws + 4702208);          // [2][2048][1536] XOR (W2|U2)
    bf16* Wdt   = (bf16*)(ws + 17285120);         // [1024][1024]    XOR
    bf16* hA    = (bf16*)(ws + 19382272);         // [2048][512]     XOR
    bf16* hB    = (bf16*)(ws + 21479424);         // [2048][512]     XOR
    float* cst  = (float*)(ws + 23576576);        // [2048][512] f32
    bf16* dbuf  = (bf16*)(ws + 27770880);         // [1024][1024]
    bf16* h1seq = (bf16*)(ws + 29868032);         // [64][1024][1024] XOR
    // end: 164,085,760 bytes

    // ---- prep: tables + weight transposes (gate-interleave + XOR) ----
    k_embw<<<dim3(8, 30, 2), 256, 0, stream>>>(emb, W1f, b1f, W1b, b1b, embW);
    k_b2r<<<16, 256, 0, stream>>>(b2f, b2b, b2r);
    k_trans<1, 1><<<dim3(8, 32), 256, 0, stream>>>(U1f, Ut1,              2048, 512, 0);
    k_trans<1, 1><<<dim3(8, 32), 256, 0, stream>>>(U1b, Ut1 + 2048 * 512, 2048, 512, 0);
    k_trans<1, 1><<<dim3(16, 32), 256, 0, stream>>>(W2f, BigBt,                2048, 1536, 0);
    k_trans<1, 1><<<dim3(8, 32), 256, 0, stream>>>(U2f, BigBt,                2048, 1536, 1024);
    k_trans<1, 1><<<dim3(16, 32), 256, 0, stream>>>(W2b, BigBt + 2048 * 1536, 2048, 1536, 0);
    k_trans<1, 1><<<dim3(8, 32), 256, 0, stream>>>(U2b, BigBt + 2048 * 1536, 2048, 1536, 1024);
    k_trans<0, 1><<<dim3(16, 16), 256, 0, stream>>>(Wd, Wdt, 1024, 1024, 0);

    // ---- layer 1 (64 per-step launches, grid 512 = 2 blocks/CU) ----
    hipMemsetAsync(hA, 0, (size_t)2048 * 512 * sizeof(bf16), stream);
    hipMemsetAsync(cst, 0, (size_t)2048 * 512 * sizeof(float), stream);
    bf16 *hin = hA, *hout = hB;
    for (int t = 0; t < 64; ++t) {
        k_step<0><<<512, 256, 0, stream>>>(
            hin, (const bf16*)nullptr, Ut1, embW, x, cst, hout, h1seq, t);
        bf16* tmp = hin; hin = hout; hout = tmp;
    }

    // ---- layer 2 (K = 1024 W2 + 512 recurrent) ----
    hipMemsetAsync(hin, 0, (size_t)2048 * 512 * sizeof(bf16), stream);
    hipMemsetAsync(cst, 0, (size_t)2048 * 512 * sizeof(float), stream);
    for (int t = 0; t < 64; ++t) {
        k_step<1><<<512, 256, 0, stream>>>(
            h1seq, hin, BigBt, b2r, (const int*)nullptr, cst, hout,
            (bf16*)nullptr, t);
        bf16* tmp = hin; hin = hout; hout = tmp;
    }
    // hin holds final layer-2 hidden state [2048][512] (XOR-swizzled)

    // ---- dense + relu, then output projection ----
    k_dense<<<64, 256, 0, stream>>>(hin, Wdt, bd, dbuf);
    k_out<<<1024, 256, 0, stream>>>(dbuf, Wo, bo, (float*)d_out);
}